// Round 1
// baseline (5267.801 us; speedup 1.0000x reference)
//
#include <hip/hip_runtime.h>
#include <cstdint>

#define H_DIM 512
#define B_DIM 256
#define T_DIM 256

// =====================================================================
// K1: Ux[(t*256 + b)*512 + i] = sum_k x[b][t][k] * U[i][k] + bias[i]
// 128x128 output tile, BK=16, 256 threads, 8x8 register tiles.
// =====================================================================
__global__ __launch_bounds__(256) void k1_ux(const float* __restrict__ x,
                                             const float* __restrict__ U,
                                             const float* __restrict__ bias,
                                             float* __restrict__ Ux) {
  __shared__ float xs[16][132];  // [k][row]  (132: pad, rows 16B-aligned)
  __shared__ float us[16][132];  // [k][col]
  const int tid = threadIdx.x;
  const int tx = tid & 15;
  const int ty = tid >> 4;
  const int r0 = blockIdx.x * 128;  // output row tile (r = t*256 + b)
  const int i0 = blockIdx.y * 128;  // output col tile
  const int t  = r0 >> 8;
  const int b0 = r0 & 255;

  float acc[8][8];
#pragma unroll
  for (int i = 0; i < 8; ++i)
#pragma unroll
    for (int q = 0; q < 8; ++q) acc[i][q] = 0.0f;

  for (int k0 = 0; k0 < H_DIM; k0 += 16) {
    __syncthreads();
#pragma unroll
    for (int n = 0; n < 2; ++n) {
      const int f4  = n * 256 + tid;   // 512 float4 per operand tile
      const int rr  = f4 >> 2;
      const int kk4 = f4 & 3;
      const float4 xv = *(const float4*)(x + ((size_t)(b0 + rr) * T_DIM + t) * H_DIM + k0 + kk4 * 4);
      xs[kk4 * 4 + 0][rr] = xv.x;
      xs[kk4 * 4 + 1][rr] = xv.y;
      xs[kk4 * 4 + 2][rr] = xv.z;
      xs[kk4 * 4 + 3][rr] = xv.w;
      const float4 uv = *(const float4*)(U + (size_t)(i0 + rr) * H_DIM + k0 + kk4 * 4);
      us[kk4 * 4 + 0][rr] = uv.x;
      us[kk4 * 4 + 1][rr] = uv.y;
      us[kk4 * 4 + 2][rr] = uv.z;
      us[kk4 * 4 + 3][rr] = uv.w;
    }
    __syncthreads();
#pragma unroll
    for (int kk = 0; kk < 16; ++kk) {
      const float4 xa = *(const float4*)&xs[kk][ty * 8];
      const float4 xb = *(const float4*)&xs[kk][ty * 8 + 4];
      const float4 ua = *(const float4*)&us[kk][tx * 8];
      const float4 ub = *(const float4*)&us[kk][tx * 8 + 4];
      const float xr[8] = {xa.x, xa.y, xa.z, xa.w, xb.x, xb.y, xb.z, xb.w};
      const float ur[8] = {ua.x, ua.y, ua.z, ua.w, ub.x, ub.y, ub.z, ub.w};
#pragma unroll
      for (int i = 0; i < 8; ++i)
#pragma unroll
        for (int q = 0; q < 8; ++q) acc[i][q] = fmaf(xr[i], ur[q], acc[i][q]);
    }
  }

  const float4 bv0 = *(const float4*)(bias + i0 + tx * 8);
  const float4 bv1 = *(const float4*)(bias + i0 + tx * 8 + 4);
  const float bb[8] = {bv0.x, bv0.y, bv0.z, bv0.w, bv1.x, bv1.y, bv1.z, bv1.w};
#pragma unroll
  for (int i = 0; i < 8; ++i) {
    float4 o0, o1;
    o0.x = acc[i][0] + bb[0]; o0.y = acc[i][1] + bb[1];
    o0.z = acc[i][2] + bb[2]; o0.w = acc[i][3] + bb[3];
    o1.x = acc[i][4] + bb[4]; o1.y = acc[i][5] + bb[5];
    o1.z = acc[i][6] + bb[6]; o1.w = acc[i][7] + bb[7];
    float* dst = Ux + (size_t)(r0 + ty * 8 + i) * H_DIM + i0 + tx * 8;
    *(float4*)dst = o0;
    *(float4*)(dst + 4) = o1;
  }
}

// =====================================================================
// K2: sequential scan. 256 blocks x 512 threads.
//   block = (g = bid>>5: batch group of 32, f = bid&31: 16-feature slice)
//   LDS (128 KiB dynamic): M[32][512] = [W-slice(16 rows); A-slice(16 rows)],
//                          y[32][512] = group's current state.
//   Per step: out[b][r] = sum_k y[b][k]*M[r][k]; 8x8 reg tiles, 32-way K-split
//   over lanes (c = tid&31 -> lane-contiguous ds_read_b128, conflict-free),
//   recursive-halving reduce (62 shuffles) so lane c ends with o = {2c,2c+1};
//   h-bit (lane^32) pairs the W-tile with the matching A-tile.
//   Group sync: monotonic agent-scope counter, arrive 32/step.
// =====================================================================
__global__ __launch_bounds__(512) void k2_scan(const float* __restrict__ W,
                                               const float* __restrict__ A,
                                               const float* __restrict__ y0,
                                               const float* __restrict__ Ux,
                                               const float* __restrict__ Wro,
                                               float* __restrict__ ybuf,          // 2 * 256*512
                                               float* __restrict__ plog,          // [T][64][B]
                                               unsigned int* __restrict__ cnt) {  // 8 groups, stride 32
  extern __shared__ float smem[];
  float* M_lds = smem;               // 32*512
  float* y_lds = smem + 32 * 512;    // 32*512

  const int tid = threadIdx.x;
  const int f   = blockIdx.x & 31;
  const int g   = blockIdx.x >> 5;
  const int c   = tid & 31;          // K-split lane
  const int h   = (tid >> 5) & 1;    // 0 = W(pre) tile, 1 = A(gate) tile
  const int w   = tid >> 6;          // wave 0..7
  const int bg  = w >> 1;            // batch sub-group 0..3 (8 batches)
  const int u   = w & 1;             // feature octet 0..1
  const int rg  = u + 2 * h;         // M row group (rows rg*8..rg*8+7)
  const int fbase = f * 16;

  // ---- load W/A slices into LDS (once) ----
#pragma unroll
  for (int n = 0; n < 8; ++n) {
    const int f4  = n * 512 + tid;   // 4096 float4
    const int row = f4 >> 7;
    const int col = (f4 & 127) * 4;
    const float* src = (row < 16) ? (W + (size_t)(fbase + row) * H_DIM + col)
                                  : (A + (size_t)(fbase + row - 16) * H_DIM + col);
    *(float4*)(M_lds + row * 512 + col) = *(const float4*)src;
  }

  const int o_mine = 2 * c + h;      // this thread's output within (bg,u) 8x8 block
  const int b_i    = o_mine >> 3;
  const int q_m    = o_mine & 7;
  const int f_loc  = u * 8 + q_m;    // 0..15
  const int b_loc  = bg * 8 + b_i;   // 0..31
  const int b_glob = g * 32 + b_loc;
  const float wro_s = Wro[fbase + f_loc];

  __syncthreads();

  for (int t = 0; t < T_DIM; ++t) {
    // ---- acquire y_t (written by all 32 blocks of this group) ----
    if (t > 0) {
      if (tid == 0) {
        const unsigned int target = 32u * (unsigned int)t;
        while (__hip_atomic_load(cnt + g * 32, __ATOMIC_ACQUIRE, __HIP_MEMORY_SCOPE_AGENT) < target)
          __builtin_amdgcn_s_sleep(1);
      }
      __syncthreads();
    }
    // ---- stage y tile (32 rows x 512) ----
    const float* ysrc = (t == 0) ? (y0 + (size_t)g * 32 * H_DIM)
                                 : (ybuf + (size_t)(t & 1) * (B_DIM * H_DIM) + (size_t)g * 32 * H_DIM);
#pragma unroll
    for (int n = 0; n < 8; ++n) {
      const int f4 = n * 512 + tid;
      *(float4*)(y_lds + f4 * 4) = *(const float4*)(ysrc + f4 * 4);
    }
    // prefetch input-path term (used in epilogue; latency hidden under K-loop)
    const float ux = Ux[((size_t)t * B_DIM + b_glob) * H_DIM + fbase + f_loc];
    __syncthreads();

    // ---- K-loop: v[i*8+q] = partial over k in {4c+128j .. +3} ----
    float v[64];
#pragma unroll
    for (int z = 0; z < 64; ++z) v[z] = 0.0f;
#pragma unroll
    for (int j = 0; j < 4; ++j) {
      const int kq = 4 * c + 128 * j;
      float4 yv[8], mv[8];
#pragma unroll
      for (int i = 0; i < 8; ++i)
        yv[i] = *(const float4*)(y_lds + (bg * 8 + i) * 512 + kq);
#pragma unroll
      for (int qq = 0; qq < 8; ++qq)
        mv[qq] = *(const float4*)(M_lds + (rg * 8 + qq) * 512 + kq);
#pragma unroll
      for (int i = 0; i < 8; ++i)
#pragma unroll
        for (int qq = 0; qq < 8; ++qq) {
          float s = v[i * 8 + qq];
          s = fmaf(yv[i].x, mv[qq].x, s);
          s = fmaf(yv[i].y, mv[qq].y, s);
          s = fmaf(yv[i].z, mv[qq].z, s);
          s = fmaf(yv[i].w, mv[qq].w, s);
          v[i * 8 + qq] = s;
        }
    }

    // ---- recursive-halving reduce over the 32 c-lanes ----
    // step s: resolve output bit (s+1) against c bit s; sizes 64->32->...->2
#pragma unroll
    for (int s = 4; s >= 0; --s) {
      const int half = 1 << (s + 1);
      const bool sel = (c >> s) & 1;
#pragma unroll
      for (int p = 0; p < half; ++p) {
        const float send = sel ? v[p] : v[p + half];
        const float keep = sel ? v[p + half] : v[p];
        v[p] = keep + __shfl_xor(send, 1 << s, 64);
      }
    }
    // v[0] = full dot for o=2c, v[1] = o=2c+1 (of this thread's tile type h)
    const float r0 = __shfl_xor(v[0], 32, 64);
    const float r1 = __shfl_xor(v[1], 32, 64);
    const float pre_v  = h ? r1 : v[0];
    const float gate_v = h ? v[1] : r0;

    const float y_old = y_lds[b_loc * 512 + fbase + f_loc];
    const float th    = tanhf(pre_v + ux);
    const float gate  = 1.0f / (1.0f + expf(-gate_v));
    const float ynew  = y_old + 0.1f * th * gate;

    float* ydst = ybuf + (size_t)((t + 1) & 1) * (B_DIM * H_DIM);
    ydst[(size_t)b_glob * H_DIM + fbase + f_loc] = ynew;

    // readout partial: sum over this (bg,u,b_i)'s 8 features
    float p = ynew * wro_s;
    p += __shfl_xor(p, 1, 64);
    p += __shfl_xor(p, 2, 64);
    p += __shfl_xor(p, 32, 64);
    if (h == 0 && (c & 3) == 0) {
      plog[((size_t)t * 64 + (f * 2 + u)) * B_DIM + b_glob] = p;
    }

    // ---- publish y_{t+1}: drain stores (barrier), flush L2, arrive ----
    __syncthreads();
    if (tid == 0) {
      __threadfence();
      __hip_atomic_fetch_add(cnt + g * 32, 1u, __ATOMIC_RELEASE, __HIP_MEMORY_SCOPE_AGENT);
    }
  }
}

// =====================================================================
// K3: out[b][t] = bro + sum_{col<64} plog[t][col][b]
// =====================================================================
__global__ __launch_bounds__(256) void k3_out(const float* __restrict__ plog,
                                              const float* __restrict__ bro,
                                              float* __restrict__ out) {
  const int t = blockIdx.x;
  const int b = threadIdx.x;
  float s = bro[0];
#pragma unroll
  for (int col = 0; col < 64; ++col)
    s += plog[((size_t)t * 64 + col) * B_DIM + b];
  out[(size_t)b * T_DIM + t] = s;
}

// =====================================================================
extern "C" void kernel_launch(void* const* d_in, const int* in_sizes, int n_in,
                              void* d_out, int out_size, void* d_ws, size_t ws_size,
                              hipStream_t stream) {
  const float* x   = (const float*)d_in[0];
  const float* y0  = (const float*)d_in[1];
  const float* W   = (const float*)d_in[2];
  const float* U   = (const float*)d_in[3];
  const float* b   = (const float*)d_in[4];
  const float* A   = (const float*)d_in[5];
  const float* Wro = (const float*)d_in[6];
  const float* bro = (const float*)d_in[7];
  float* out = (float*)d_out;

  float* ws = (float*)d_ws;
  float* Ux   = ws;                                   // 256*256*512      = 33,554,432 f32
  float* ybuf = Ux + (size_t)T_DIM * B_DIM * H_DIM;   // 2*256*512        = 262,144 f32
  float* plog = ybuf + (size_t)2 * B_DIM * H_DIM;     // 256*64*256       = 4,194,304 f32
  unsigned int* cnt = (unsigned int*)(plog + (size_t)T_DIM * 64 * B_DIM);  // 8*32 u32

  (void)in_sizes; (void)n_in; (void)out_size; (void)ws_size;

  hipFuncSetAttribute(reinterpret_cast<const void*>(k2_scan),
                      hipFuncAttributeMaxDynamicSharedMemorySize, 131072);
  hipMemsetAsync(cnt, 0, 8 * 32 * sizeof(unsigned int), stream);

  dim3 g1(512, 4);
  k1_ux<<<g1, 256, 0, stream>>>(x, U, b, Ux);
  k2_scan<<<256, 512, 131072, stream>>>(W, A, y0, Ux, Wro, ybuf, plog, cnt);
  k3_out<<<256, 256, 0, stream>>>(plog, bro, out);
}

// Round 2
// 3572.720 us; speedup vs baseline: 1.4745x; 1.4745x over previous
//
#include <hip/hip_runtime.h>
#include <cstdint>

#define H_DIM 512
#define B_DIM 256
#define T_DIM 256

typedef __bf16 bf16x8 __attribute__((ext_vector_type(8)));
typedef __bf16 bf16x4 __attribute__((ext_vector_type(4)));
typedef float  f32x4  __attribute__((ext_vector_type(4)));

// =====================================================================
// K1: Ux[(t*256 + b)*512 + i] = sum_k x[b][t][k] * U[i][k] + bias[i]
// 128x128 output tile, BK=16, 256 threads, 8x8 register tiles. (f32 VALU)
// =====================================================================
__global__ __launch_bounds__(256) void k1_ux(const float* __restrict__ x,
                                             const float* __restrict__ U,
                                             const float* __restrict__ bias,
                                             float* __restrict__ Ux) {
  __shared__ float xs[16][132];
  __shared__ float us[16][132];
  const int tid = threadIdx.x;
  const int tx = tid & 15;
  const int ty = tid >> 4;
  const int r0 = blockIdx.x * 128;
  const int i0 = blockIdx.y * 128;
  const int t  = r0 >> 8;
  const int b0 = r0 & 255;

  float acc[8][8];
#pragma unroll
  for (int i = 0; i < 8; ++i)
#pragma unroll
    for (int q = 0; q < 8; ++q) acc[i][q] = 0.0f;

  for (int k0 = 0; k0 < H_DIM; k0 += 16) {
    __syncthreads();
#pragma unroll
    for (int n = 0; n < 2; ++n) {
      const int f4  = n * 256 + tid;
      const int rr  = f4 >> 2;
      const int kk4 = f4 & 3;
      const float4 xv = *(const float4*)(x + ((size_t)(b0 + rr) * T_DIM + t) * H_DIM + k0 + kk4 * 4);
      xs[kk4 * 4 + 0][rr] = xv.x;
      xs[kk4 * 4 + 1][rr] = xv.y;
      xs[kk4 * 4 + 2][rr] = xv.z;
      xs[kk4 * 4 + 3][rr] = xv.w;
      const float4 uv = *(const float4*)(U + (size_t)(i0 + rr) * H_DIM + k0 + kk4 * 4);
      us[kk4 * 4 + 0][rr] = uv.x;
      us[kk4 * 4 + 1][rr] = uv.y;
      us[kk4 * 4 + 2][rr] = uv.z;
      us[kk4 * 4 + 3][rr] = uv.w;
    }
    __syncthreads();
#pragma unroll
    for (int kk = 0; kk < 16; ++kk) {
      const float4 xa = *(const float4*)&xs[kk][ty * 8];
      const float4 xb = *(const float4*)&xs[kk][ty * 8 + 4];
      const float4 ua = *(const float4*)&us[kk][tx * 8];
      const float4 ub = *(const float4*)&us[kk][tx * 8 + 4];
      const float xr[8] = {xa.x, xa.y, xa.z, xa.w, xb.x, xb.y, xb.z, xb.w};
      const float ur[8] = {ua.x, ua.y, ua.z, ua.w, ub.x, ub.y, ub.z, ub.w};
#pragma unroll
      for (int i = 0; i < 8; ++i)
#pragma unroll
        for (int q = 0; q < 8; ++q) acc[i][q] = fmaf(xr[i], ur[q], acc[i][q]);
    }
  }

  const float4 bv0 = *(const float4*)(bias + i0 + tx * 8);
  const float4 bv1 = *(const float4*)(bias + i0 + tx * 8 + 4);
  const float bb[8] = {bv0.x, bv0.y, bv0.z, bv0.w, bv1.x, bv1.y, bv1.z, bv1.w};
#pragma unroll
  for (int i = 0; i < 8; ++i) {
    float4 o0, o1;
    o0.x = acc[i][0] + bb[0]; o0.y = acc[i][1] + bb[1];
    o0.z = acc[i][2] + bb[2]; o0.w = acc[i][3] + bb[3];
    o1.x = acc[i][4] + bb[4]; o1.y = acc[i][5] + bb[5];
    o1.z = acc[i][6] + bb[6]; o1.w = acc[i][7] + bb[7];
    float* dst = Ux + (size_t)(r0 + ty * 8 + i) * H_DIM + i0 + tx * 8;
    *(float4*)dst = o0;
    *(float4*)(dst + 4) = o1;
  }
}

// =====================================================================
// K2: scan. 128 blocks x 256 threads. bid = slice*8 + g  (g = XCD-local group)
//   group g: 32 batches; slice: 32 features. Per block LDS:
//     M (bf16, swizzled)  [64][512]  : rows 0..31 = W-slice, 32..63 = A-slice (64 KB)
//     Y (bf16, swizzled)  [32][512]  : group's y_t as bf16                    (32 KB)
//     X (f32)  [4][32][32]           : per-wave partial tiles                 (16 KB)
//     O (f32)  [32][32]              : own y state, exact f32, persistent     (4 KB)
//   Per step: 4 waves, wave w: otype=w>>1 (pre/gate), khalf=w&1 (K 256-split);
//   each wave 2Mx2Nx8K = 32 x mfma_f32_16x16x32_bf16; 2-way K-reduce + gate
//   exchange via X; epilogue per-thread (b = tid>>3, f = (tid&7)*4 .. +4).
//   Sync: per-block monotone flag (release store); 16-lane parallel spin.
// =====================================================================
#define LDS_M 0
#define LDS_Y 65536
#define LDS_X 98304
#define LDS_O 114688
#define LDS_TOTAL 118784

__device__ __forceinline__ unsigned swz(unsigned row, unsigned kb) {
  return row * 1024u + (kb ^ ((row & 7u) << 4));
}

__global__ __launch_bounds__(256, 1) void k2_scan(const float* __restrict__ W,
                                                  const float* __restrict__ Amat,
                                                  const float* __restrict__ y0,
                                                  const float* __restrict__ Ux,
                                                  const float* __restrict__ Wro,
                                                  __bf16* __restrict__ ybuf,      // 2*256*512 bf16
                                                  float* __restrict__ plog,       // [T][16][B]
                                                  unsigned int* __restrict__ flags) {  // 128 * 32
  extern __shared__ char smem[];
  const int tid   = threadIdx.x;
  const int g     = blockIdx.x & 7;
  const int slice = blockIdx.x >> 3;
  const int fbase = slice * 32;

  const int l = tid & 63;
  const int w = tid >> 6;
  const int otype = w >> 1;
  const int khalf = w & 1;

  // ---- stage W/A slice -> M (bf16, swizzled), once ----
#pragma unroll
  for (int jj = 0; jj < 16; ++jj) {
    const int chunk = jj * 256 + tid;   // 4096 x 16B bf16 chunks
    const int row   = chunk >> 6;
    const int inner = chunk & 63;
    const float* src = (row < 32) ? (W + (size_t)(fbase + row) * H_DIM + inner * 8)
                                  : (Amat + (size_t)(fbase + row - 32) * H_DIM + inner * 8);
    const float4 s0 = *(const float4*)src;
    const float4 s1 = *(const float4*)(src + 4);
    bf16x8 v;
    v[0] = (__bf16)s0.x; v[1] = (__bf16)s0.y; v[2] = (__bf16)s0.z; v[3] = (__bf16)s0.w;
    v[4] = (__bf16)s1.x; v[5] = (__bf16)s1.y; v[6] = (__bf16)s1.z; v[7] = (__bf16)s1.w;
    *(bf16x8*)(smem + LDS_M + swz(row, inner * 16)) = v;
  }

  // ---- init own f32 y state ----
  const int bl  = tid >> 3;          // batch 0..31
  const int f0i = (tid & 7) * 4;     // feature 0..28
  const int b_glob = g * 32 + bl;
  {
    const float4 yv = *(const float4*)(y0 + (size_t)b_glob * H_DIM + fbase + f0i);
    *(float4*)(smem + LDS_O + bl * 128 + f0i * 4) = yv;
  }
  const float4 wrov = *(const float4*)(Wro + fbase + f0i);
  __syncthreads();

  // frag row/col constants
  const unsigned ra0 = (unsigned)(l & 15);
  const unsigned ra1 = ra0 + 16u;
  const unsigned rb0 = (unsigned)(otype * 32 + (l & 15));
  const unsigned rb1 = rb0 + 16u;
  const unsigned coff = (unsigned)((l >> 4) * 16 + khalf * 512);

  for (int t = 0; t < T_DIM; ++t) {
    // input-path term (no dependency on peers -> issue before spin)
    const float4 uxv = *(const float4*)(Ux + ((size_t)t * B_DIM + b_glob) * H_DIM + fbase + f0i);

    // ---- acquire: wait for all 16 peer blocks of this group at step t ----
    if (t > 0) {
      if (tid < 64) {
        const unsigned int* fp = flags + (((tid & 15) * 8 + g) * 32);
        const unsigned target = (unsigned)t;
        for (;;) {
          const unsigned v = (tid < 16)
              ? __hip_atomic_load(fp, __ATOMIC_ACQUIRE, __HIP_MEMORY_SCOPE_AGENT)
              : 0xFFFFFFFFu;
          if (__all(v >= target)) break;
          __builtin_amdgcn_s_sleep(1);
        }
      }
      __syncthreads();
      __builtin_amdgcn_fence(__ATOMIC_ACQUIRE, "agent");
    }

    // ---- stage group's y_t -> Y (bf16, swizzled) ----
    if (t == 0) {
#pragma unroll
      for (int j = 0; j < 8; ++j) {
        const int chunk = j * 256 + tid;   // 2048 x 16B chunks
        const int row   = chunk >> 6;
        const int inner = chunk & 63;
        const float* src = y0 + (size_t)(g * 32 + row) * H_DIM + inner * 8;
        const float4 s0 = *(const float4*)src;
        const float4 s1 = *(const float4*)(src + 4);
        bf16x8 v;
        v[0] = (__bf16)s0.x; v[1] = (__bf16)s0.y; v[2] = (__bf16)s0.z; v[3] = (__bf16)s0.w;
        v[4] = (__bf16)s1.x; v[5] = (__bf16)s1.y; v[6] = (__bf16)s1.z; v[7] = (__bf16)s1.w;
        *(bf16x8*)(smem + LDS_Y + swz(row, inner * 16)) = v;
      }
    } else {
      const __bf16* src_base = ybuf + (size_t)(t & 1) * (B_DIM * H_DIM) + (size_t)g * 32 * H_DIM;
#pragma unroll
      for (int j = 0; j < 8; ++j) {
        const int chunk = j * 256 + tid;
        const int row   = chunk >> 6;
        const int inner = chunk & 63;
        const bf16x8 v = *(const bf16x8*)(src_base + (size_t)row * H_DIM + inner * 8);
        *(bf16x8*)(smem + LDS_Y + swz(row, inner * 16)) = v;
      }
    }
    __syncthreads();

    // ---- MFMA K-loop: 2M x 2N x 8K per wave ----
    f32x4 acc00 = {0.f, 0.f, 0.f, 0.f};
    f32x4 acc01 = {0.f, 0.f, 0.f, 0.f};
    f32x4 acc10 = {0.f, 0.f, 0.f, 0.f};
    f32x4 acc11 = {0.f, 0.f, 0.f, 0.f};
#pragma unroll
    for (int ks = 0; ks < 8; ++ks) {
      const unsigned kb = coff + (unsigned)ks * 64u;
      const bf16x8 a0 = *(const bf16x8*)(smem + LDS_Y + swz(ra0, kb));
      const bf16x8 a1 = *(const bf16x8*)(smem + LDS_Y + swz(ra1, kb));
      const bf16x8 b0 = *(const bf16x8*)(smem + LDS_M + swz(rb0, kb));
      const bf16x8 b1 = *(const bf16x8*)(smem + LDS_M + swz(rb1, kb));
      acc00 = __builtin_amdgcn_mfma_f32_16x16x32_bf16(a0, b0, acc00, 0, 0, 0);
      acc01 = __builtin_amdgcn_mfma_f32_16x16x32_bf16(a0, b1, acc01, 0, 0, 0);
      acc10 = __builtin_amdgcn_mfma_f32_16x16x32_bf16(a1, b0, acc10, 0, 0, 0);
      acc11 = __builtin_amdgcn_mfma_f32_16x16x32_bf16(a1, b1, acc11, 0, 0, 0);
    }

    // ---- write partial tiles to X[w][b][f] ----
    {
      float* ex = (float*)(smem + LDS_X) + w * 1024;
      const int lr = (l >> 4) * 4;
      const int lc = l & 15;
#pragma unroll
      for (int r = 0; r < 4; ++r) {
        ex[(lr + r) * 32 + lc]            = acc00[r];
        ex[(lr + r) * 32 + 16 + lc]       = acc01[r];
        ex[(16 + lr + r) * 32 + lc]       = acc10[r];
        ex[(16 + lr + r) * 32 + 16 + lc]  = acc11[r];
      }
    }
    __syncthreads();

    // ---- epilogue: combine, state update, publish ----
    {
      const float* exb = (const float*)(smem + LDS_X);
      const float4 p0 = *(const float4*)(exb + 0 * 1024 + bl * 32 + f0i);
      const float4 p1 = *(const float4*)(exb + 1 * 1024 + bl * 32 + f0i);
      const float4 g0 = *(const float4*)(exb + 2 * 1024 + bl * 32 + f0i);
      const float4 g1 = *(const float4*)(exb + 3 * 1024 + bl * 32 + f0i);
      const float4 yo = *(const float4*)(smem + LDS_O + bl * 128 + f0i * 4);

      float yn[4];
      const float pr[4] = {p0.x + p1.x + uxv.x, p0.y + p1.y + uxv.y,
                           p0.z + p1.z + uxv.z, p0.w + p1.w + uxv.w};
      const float gv[4] = {g0.x + g1.x, g0.y + g1.y, g0.z + g1.z, g0.w + g1.w};
      const float yov[4] = {yo.x, yo.y, yo.z, yo.w};
#pragma unroll
      for (int j = 0; j < 4; ++j) {
        const float gate = 1.0f / (1.0f + expf(-gv[j]));
        yn[j] = yov[j] + 0.1f * tanhf(pr[j]) * gate;
      }
      float4 ynv; ynv.x = yn[0]; ynv.y = yn[1]; ynv.z = yn[2]; ynv.w = yn[3];
      *(float4*)(smem + LDS_O + bl * 128 + f0i * 4) = ynv;

      bf16x4 pk;
      pk[0] = (__bf16)yn[0]; pk[1] = (__bf16)yn[1];
      pk[2] = (__bf16)yn[2]; pk[3] = (__bf16)yn[3];
      *(bf16x4*)(ybuf + (size_t)((t + 1) & 1) * (B_DIM * H_DIM) + (size_t)b_glob * H_DIM + fbase + f0i) = pk;

      float s = yn[0] * wrov.x + yn[1] * wrov.y + yn[2] * wrov.z + yn[3] * wrov.w;
      s += __shfl_xor(s, 1, 64);
      s += __shfl_xor(s, 2, 64);
      s += __shfl_xor(s, 4, 64);
      if ((tid & 7) == 0)
        plog[((size_t)t * 16 + slice) * B_DIM + b_glob] = s;
    }

    // ---- release: drain block stores, publish flag ----
    __syncthreads();
    if (tid == 0) {
      __threadfence();
      __hip_atomic_store(flags + blockIdx.x * 32, (unsigned)(t + 1),
                         __ATOMIC_RELEASE, __HIP_MEMORY_SCOPE_AGENT);
    }
  }
}

// =====================================================================
// K3: out[b][t] = bro + sum_{s<16} plog[t][s][b]
// =====================================================================
__global__ __launch_bounds__(256) void k3_out(const float* __restrict__ plog,
                                              const float* __restrict__ bro,
                                              float* __restrict__ out) {
  const int t = blockIdx.x;
  const int b = threadIdx.x;
  float s = bro[0];
#pragma unroll
  for (int col = 0; col < 16; ++col)
    s += plog[((size_t)t * 16 + col) * B_DIM + b];
  out[(size_t)b * T_DIM + t] = s;
}

// =====================================================================
extern "C" void kernel_launch(void* const* d_in, const int* in_sizes, int n_in,
                              void* d_out, int out_size, void* d_ws, size_t ws_size,
                              hipStream_t stream) {
  const float* x   = (const float*)d_in[0];
  const float* y0  = (const float*)d_in[1];
  const float* W   = (const float*)d_in[2];
  const float* U   = (const float*)d_in[3];
  const float* b   = (const float*)d_in[4];
  const float* A   = (const float*)d_in[5];
  const float* Wro = (const float*)d_in[6];
  const float* bro = (const float*)d_in[7];
  float* out = (float*)d_out;

  float* ws = (float*)d_ws;
  float* Ux = ws;                                            // 33,554,432 f32
  __bf16* ybuf = (__bf16*)(ws + (size_t)T_DIM * B_DIM * H_DIM);  // 262,144 bf16 (131,072 f32 slots)
  float* plog = ws + (size_t)T_DIM * B_DIM * H_DIM + 131072;     // 1,048,576 f32
  unsigned int* flags = (unsigned int*)(plog + (size_t)T_DIM * 16 * B_DIM);  // 128*32 u32

  (void)in_sizes; (void)n_in; (void)out_size; (void)ws_size;

  hipFuncSetAttribute(reinterpret_cast<const void*>(k2_scan),
                      hipFuncAttributeMaxDynamicSharedMemorySize, LDS_TOTAL);
  hipMemsetAsync(flags, 0, 128 * 32 * sizeof(unsigned int), stream);

  dim3 g1(512, 4);
  k1_ux<<<g1, 256, 0, stream>>>(x, U, b, Ux);
  k2_scan<<<128, 256, LDS_TOTAL, stream>>>(W, A, y0, Ux, Wro, ybuf, plog, flags);
  k3_out<<<256, 256, 0, stream>>>(plog, bro, out);
}

// Round 3
// 2971.819 us; speedup vs baseline: 1.7726x; 1.2022x over previous
//
#include <hip/hip_runtime.h>
#include <cstdint>

#define H_DIM 512
#define B_DIM 256
#define T_DIM 256

typedef __bf16 bf16x8 __attribute__((ext_vector_type(8)));
typedef __bf16 bf16x4 __attribute__((ext_vector_type(4)));
typedef float  f32x4  __attribute__((ext_vector_type(4)));

// =====================================================================
// K1: Ux[(t*256 + b)*512 + i] = sum_k x[b][t][k] * U[i][k] + bias[i]
// 128x128 output tile, BK=16, 256 threads, 8x8 register tiles. (f32 VALU)
// =====================================================================
__global__ __launch_bounds__(256) void k1_ux(const float* __restrict__ x,
                                             const float* __restrict__ U,
                                             const float* __restrict__ bias,
                                             float* __restrict__ Ux) {
  __shared__ float xs[16][132];
  __shared__ float us[16][132];
  const int tid = threadIdx.x;
  const int tx = tid & 15;
  const int ty = tid >> 4;
  const int r0 = blockIdx.x * 128;
  const int i0 = blockIdx.y * 128;
  const int t  = r0 >> 8;
  const int b0 = r0 & 255;

  float acc[8][8];
#pragma unroll
  for (int i = 0; i < 8; ++i)
#pragma unroll
    for (int q = 0; q < 8; ++q) acc[i][q] = 0.0f;

  for (int k0 = 0; k0 < H_DIM; k0 += 16) {
    __syncthreads();
#pragma unroll
    for (int n = 0; n < 2; ++n) {
      const int f4  = n * 256 + tid;
      const int rr  = f4 >> 2;
      const int kk4 = f4 & 3;
      const float4 xv = *(const float4*)(x + ((size_t)(b0 + rr) * T_DIM + t) * H_DIM + k0 + kk4 * 4);
      xs[kk4 * 4 + 0][rr] = xv.x;
      xs[kk4 * 4 + 1][rr] = xv.y;
      xs[kk4 * 4 + 2][rr] = xv.z;
      xs[kk4 * 4 + 3][rr] = xv.w;
      const float4 uv = *(const float4*)(U + (size_t)(i0 + rr) * H_DIM + k0 + kk4 * 4);
      us[kk4 * 4 + 0][rr] = uv.x;
      us[kk4 * 4 + 1][rr] = uv.y;
      us[kk4 * 4 + 2][rr] = uv.z;
      us[kk4 * 4 + 3][rr] = uv.w;
    }
    __syncthreads();
#pragma unroll
    for (int kk = 0; kk < 16; ++kk) {
      const float4 xa = *(const float4*)&xs[kk][ty * 8];
      const float4 xb = *(const float4*)&xs[kk][ty * 8 + 4];
      const float4 ua = *(const float4*)&us[kk][tx * 8];
      const float4 ub = *(const float4*)&us[kk][tx * 8 + 4];
      const float xr[8] = {xa.x, xa.y, xa.z, xa.w, xb.x, xb.y, xb.z, xb.w};
      const float ur[8] = {ua.x, ua.y, ua.z, ua.w, ub.x, ub.y, ub.z, ub.w};
#pragma unroll
      for (int i = 0; i < 8; ++i)
#pragma unroll
        for (int q = 0; q < 8; ++q) acc[i][q] = fmaf(xr[i], ur[q], acc[i][q]);
    }
  }

  const float4 bv0 = *(const float4*)(bias + i0 + tx * 8);
  const float4 bv1 = *(const float4*)(bias + i0 + tx * 8 + 4);
  const float bb[8] = {bv0.x, bv0.y, bv0.z, bv0.w, bv1.x, bv1.y, bv1.z, bv1.w};
#pragma unroll
  for (int i = 0; i < 8; ++i) {
    float4 o0, o1;
    o0.x = acc[i][0] + bb[0]; o0.y = acc[i][1] + bb[1];
    o0.z = acc[i][2] + bb[2]; o0.w = acc[i][3] + bb[3];
    o1.x = acc[i][4] + bb[4]; o1.y = acc[i][5] + bb[5];
    o1.z = acc[i][6] + bb[6]; o1.w = acc[i][7] + bb[7];
    float* dst = Ux + (size_t)(r0 + ty * 8 + i) * H_DIM + i0 + tx * 8;
    *(float4*)dst = o0;
    *(float4*)(dst + 4) = o1;
  }
}

// =====================================================================
// K2: scan. 128 blocks x 256 threads. bid = slice*8 + g (g: XCD-local group)
//   group g = 32 batches; slice = 32 features.
//   W/A fragments: VGPR-resident (loaded once; 16 x bf16x8 per wave).
//   y_t fragments: loaded directly from global ybuf (XCD-local L2, bf16).
//   Own y state: exact f32 in LDS Ost[32][32]; X-exchange LDS [4][32][36].
//   Per step: all-wave relaxed spin -> acquire fence -> 16 L2 frag loads ->
//   32 MFMA -> X write -> barrier -> epilogue (state update, publish bf16,
//   plog partial) -> barrier -> tid0 release-store flag.
//   Flag protocol: prologue publishes y_0 (flag=1); step t publishes flag=t+2.
// =====================================================================
__global__ __launch_bounds__(256, 1) void k2_scan(const float* __restrict__ W,
                                                  const float* __restrict__ Amat,
                                                  const float* __restrict__ y0,
                                                  const float* __restrict__ Ux,
                                                  const float* __restrict__ Wro,
                                                  __bf16* __restrict__ ybuf,      // 2*256*512 bf16
                                                  float* __restrict__ plog,       // [T][16][B]
                                                  unsigned int* __restrict__ flags) {  // 128 * 32
  __shared__ float Xex[4][32][36];   // padded stride: conflict-free
  __shared__ float Ost[32][32];      // own f32 state

  const int tid   = threadIdx.x;
  const int g     = blockIdx.x & 7;
  const int slice = blockIdx.x >> 3;
  const int fbase = slice * 32;

  const int l     = tid & 63;
  const int w     = tid >> 6;
  const int otype = w >> 1;          // 0 = pre (W), 1 = gate (A)
  const int khalf = w & 1;           // K 256-split

  const int bl     = tid >> 3;       // batch 0..31
  const int f0i    = (tid & 7) * 4;  // feature 0..28
  const int b_glob = g * 32 + bl;

  // ---- prologue: own y0 tile -> Ost (f32) and ybuf[0] (bf16) ----
  {
    const float4 yv = *(const float4*)(y0 + (size_t)b_glob * H_DIM + fbase + f0i);
    *(float4*)&Ost[bl][f0i] = yv;
    bf16x4 pk;
    pk[0] = (__bf16)yv.x; pk[1] = (__bf16)yv.y;
    pk[2] = (__bf16)yv.z; pk[3] = (__bf16)yv.w;
    *(bf16x4*)(ybuf + (size_t)b_glob * H_DIM + fbase + f0i) = pk;
  }
  const float4 wrov = *(const float4*)(Wro + fbase + f0i);

  // ---- W/A fragments -> VGPRs (once; they never change) ----
  const int n0    = l & 15;                         // N index within slice
  const int kfrag = khalf * 256 + ((l >> 4) * 8);   // per-lane K base (elems)
  const float* Bsrc = otype ? Amat : W;
  bf16x8 bfr[2][8];
#pragma unroll
  for (int ks = 0; ks < 8; ++ks) {
#pragma unroll
    for (int h2 = 0; h2 < 2; ++h2) {
      const float* src = Bsrc + (size_t)(fbase + n0 + h2 * 16) * H_DIM + kfrag + ks * 32;
      const float4 s0 = *(const float4*)src;
      const float4 s1 = *(const float4*)(src + 4);
      bf16x8 v;
      v[0] = (__bf16)s0.x; v[1] = (__bf16)s0.y; v[2] = (__bf16)s0.z; v[3] = (__bf16)s0.w;
      v[4] = (__bf16)s1.x; v[5] = (__bf16)s1.y; v[6] = (__bf16)s1.z; v[7] = (__bf16)s1.w;
      bfr[h2][ks] = v;
    }
  }

  __syncthreads();
  if (tid == 0)
    __hip_atomic_store(flags + blockIdx.x * 32, 1u,
                       __ATOMIC_RELEASE, __HIP_MEMORY_SCOPE_AGENT);

  const unsigned int* fp = flags + ((size_t)((l & 15) * 8 + g)) * 32;

  for (int t = 0; t < T_DIM; ++t) {
    // input-path term: issue before spin (latency hides under the wait)
    const float4 uxv = *(const float4*)(Ux + ((size_t)t * B_DIM + b_glob) * H_DIM + fbase + f0i);

    // ---- all-wave relaxed spin: y_t published by all 16 peers? ----
    {
      const unsigned target = (unsigned)(t + 1);
      for (;;) {
        unsigned v = target;
        if (l < 16)
          v = __hip_atomic_load(fp, __ATOMIC_RELAXED, __HIP_MEMORY_SCOPE_AGENT);
        if (__all(v >= target)) break;
        __builtin_amdgcn_s_sleep(1);
      }
    }
    __builtin_amdgcn_fence(__ATOMIC_ACQUIRE, "agent");

    // ---- y_t fragments direct from global (XCD-local L2) ----
    const __bf16* ycur = ybuf + (size_t)(t & 1) * (B_DIM * H_DIM);
    const __bf16* yr0 = ycur + (size_t)(g * 32 + n0) * H_DIM + kfrag;
    const __bf16* yr1 = yr0 + 16 * H_DIM;
    bf16x8 a0[8], a1[8];
#pragma unroll
    for (int ks = 0; ks < 8; ++ks) {
      a0[ks] = *(const bf16x8*)(yr0 + ks * 32);
      a1[ks] = *(const bf16x8*)(yr1 + ks * 32);
    }

    // ---- MFMA: 2M x 2N x 8K ----
    f32x4 acc00 = {0.f, 0.f, 0.f, 0.f};
    f32x4 acc01 = {0.f, 0.f, 0.f, 0.f};
    f32x4 acc10 = {0.f, 0.f, 0.f, 0.f};
    f32x4 acc11 = {0.f, 0.f, 0.f, 0.f};
#pragma unroll
    for (int ks = 0; ks < 8; ++ks) {
      acc00 = __builtin_amdgcn_mfma_f32_16x16x32_bf16(a0[ks], bfr[0][ks], acc00, 0, 0, 0);
      acc01 = __builtin_amdgcn_mfma_f32_16x16x32_bf16(a0[ks], bfr[1][ks], acc01, 0, 0, 0);
      acc10 = __builtin_amdgcn_mfma_f32_16x16x32_bf16(a1[ks], bfr[0][ks], acc10, 0, 0, 0);
      acc11 = __builtin_amdgcn_mfma_f32_16x16x32_bf16(a1[ks], bfr[1][ks], acc11, 0, 0, 0);
    }

    // ---- partial-tile exchange ----
    {
      const int lr = (l >> 4) * 4;
      const int lc = l & 15;
#pragma unroll
      for (int r = 0; r < 4; ++r) {
        Xex[w][lr + r][lc]           = acc00[r];
        Xex[w][lr + r][lc + 16]      = acc01[r];
        Xex[w][lr + r + 16][lc]      = acc10[r];
        Xex[w][lr + r + 16][lc + 16] = acc11[r];
      }
    }
    __syncthreads();

    // ---- epilogue: combine halves, state update, publish ----
    {
      const float4 p0 = *(const float4*)&Xex[0][bl][f0i];
      const float4 p1 = *(const float4*)&Xex[1][bl][f0i];
      const float4 g0 = *(const float4*)&Xex[2][bl][f0i];
      const float4 g1 = *(const float4*)&Xex[3][bl][f0i];
      const float4 yo = *(const float4*)&Ost[bl][f0i];

      const float pr[4] = {p0.x + p1.x + uxv.x, p0.y + p1.y + uxv.y,
                           p0.z + p1.z + uxv.z, p0.w + p1.w + uxv.w};
      const float gv[4] = {g0.x + g1.x, g0.y + g1.y, g0.z + g1.z, g0.w + g1.w};
      const float yov[4] = {yo.x, yo.y, yo.z, yo.w};
      float yn[4];
#pragma unroll
      for (int j = 0; j < 4; ++j) {
        const float gate = 1.0f / (1.0f + expf(-gv[j]));
        yn[j] = yov[j] + 0.1f * tanhf(pr[j]) * gate;
      }
      float4 ynv; ynv.x = yn[0]; ynv.y = yn[1]; ynv.z = yn[2]; ynv.w = yn[3];
      *(float4*)&Ost[bl][f0i] = ynv;

      bf16x4 pk;
      pk[0] = (__bf16)yn[0]; pk[1] = (__bf16)yn[1];
      pk[2] = (__bf16)yn[2]; pk[3] = (__bf16)yn[3];
      *(bf16x4*)(ybuf + (size_t)((t + 1) & 1) * (B_DIM * H_DIM)
                 + (size_t)b_glob * H_DIM + fbase + f0i) = pk;

      float s = yn[0] * wrov.x + yn[1] * wrov.y + yn[2] * wrov.z + yn[3] * wrov.w;
      s += __shfl_xor(s, 1, 64);
      s += __shfl_xor(s, 2, 64);
      s += __shfl_xor(s, 4, 64);
      if ((tid & 7) == 0)
        plog[((size_t)t * 16 + slice) * B_DIM + b_glob] = s;
    }

    // ---- release: barrier drains all threads' stores, then publish ----
    __syncthreads();
    if (tid == 0)
      __hip_atomic_store(flags + blockIdx.x * 32, (unsigned)(t + 2),
                         __ATOMIC_RELEASE, __HIP_MEMORY_SCOPE_AGENT);
  }
}

// =====================================================================
// K3: out[b][t] = bro + sum_{s<16} plog[t][s][b]
// =====================================================================
__global__ __launch_bounds__(256) void k3_out(const float* __restrict__ plog,
                                              const float* __restrict__ bro,
                                              float* __restrict__ out) {
  const int t = blockIdx.x;
  const int b = threadIdx.x;
  float s = bro[0];
#pragma unroll
  for (int col = 0; col < 16; ++col)
    s += plog[((size_t)t * 16 + col) * B_DIM + b];
  out[(size_t)b * T_DIM + t] = s;
}

// =====================================================================
extern "C" void kernel_launch(void* const* d_in, const int* in_sizes, int n_in,
                              void* d_out, int out_size, void* d_ws, size_t ws_size,
                              hipStream_t stream) {
  const float* x   = (const float*)d_in[0];
  const float* y0  = (const float*)d_in[1];
  const float* W   = (const float*)d_in[2];
  const float* U   = (const float*)d_in[3];
  const float* b   = (const float*)d_in[4];
  const float* A   = (const float*)d_in[5];
  const float* Wro = (const float*)d_in[6];
  const float* bro = (const float*)d_in[7];
  float* out = (float*)d_out;

  float* ws = (float*)d_ws;
  float* Ux = ws;                                               // 33,554,432 f32
  __bf16* ybuf = (__bf16*)(ws + (size_t)T_DIM * B_DIM * H_DIM); // 262,144 bf16
  float* plog = ws + (size_t)T_DIM * B_DIM * H_DIM + 131072;    // 1,048,576 f32
  unsigned int* flags = (unsigned int*)(plog + (size_t)T_DIM * 16 * B_DIM);  // 128*32 u32

  (void)in_sizes; (void)n_in; (void)out_size; (void)ws_size;

  hipMemsetAsync(flags, 0, 128 * 32 * sizeof(unsigned int), stream);

  dim3 g1(512, 4);
  k1_ux<<<g1, 256, 0, stream>>>(x, U, b, Ux);
  k2_scan<<<128, 256, 0, stream>>>(W, A, y0, Ux, Wro, ybuf, plog, flags);
  k3_out<<<256, 256, 0, stream>>>(plog, bro, out);
}

// Round 4
// 1511.890 us; speedup vs baseline: 3.4842x; 1.9656x over previous
//
#include <hip/hip_runtime.h>
#include <cstdint>

#define H_DIM 512
#define B_DIM 256
#define T_DIM 256

typedef __bf16 bf16x8 __attribute__((ext_vector_type(8)));
typedef __bf16 bf16x4 __attribute__((ext_vector_type(4)));
typedef float  f32x4  __attribute__((ext_vector_type(4)));
typedef unsigned long long ull;

// =====================================================================
// K1: Ux[(t*256 + b)*512 + i] = sum_k x[b][t][k] * U[i][k] + bias[i]
// 128x128 output tile, BK=16, 256 threads, 8x8 register tiles. (f32 VALU)
// =====================================================================
__global__ __launch_bounds__(256) void k1_ux(const float* __restrict__ x,
                                             const float* __restrict__ U,
                                             const float* __restrict__ bias,
                                             float* __restrict__ Ux) {
  __shared__ float xs[16][132];
  __shared__ float us[16][132];
  const int tid = threadIdx.x;
  const int tx = tid & 15;
  const int ty = tid >> 4;
  const int r0 = blockIdx.x * 128;
  const int i0 = blockIdx.y * 128;
  const int t  = r0 >> 8;
  const int b0 = r0 & 255;

  float acc[8][8];
#pragma unroll
  for (int i = 0; i < 8; ++i)
#pragma unroll
    for (int q = 0; q < 8; ++q) acc[i][q] = 0.0f;

  for (int k0 = 0; k0 < H_DIM; k0 += 16) {
    __syncthreads();
#pragma unroll
    for (int n = 0; n < 2; ++n) {
      const int f4  = n * 256 + tid;
      const int rr  = f4 >> 2;
      const int kk4 = f4 & 3;
      const float4 xv = *(const float4*)(x + ((size_t)(b0 + rr) * T_DIM + t) * H_DIM + k0 + kk4 * 4);
      xs[kk4 * 4 + 0][rr] = xv.x;
      xs[kk4 * 4 + 1][rr] = xv.y;
      xs[kk4 * 4 + 2][rr] = xv.z;
      xs[kk4 * 4 + 3][rr] = xv.w;
      const float4 uv = *(const float4*)(U + (size_t)(i0 + rr) * H_DIM + k0 + kk4 * 4);
      us[kk4 * 4 + 0][rr] = uv.x;
      us[kk4 * 4 + 1][rr] = uv.y;
      us[kk4 * 4 + 2][rr] = uv.z;
      us[kk4 * 4 + 3][rr] = uv.w;
    }
    __syncthreads();
#pragma unroll
    for (int kk = 0; kk < 16; ++kk) {
      const float4 xa = *(const float4*)&xs[kk][ty * 8];
      const float4 xb = *(const float4*)&xs[kk][ty * 8 + 4];
      const float4 ua = *(const float4*)&us[kk][tx * 8];
      const float4 ub = *(const float4*)&us[kk][tx * 8 + 4];
      const float xr[8] = {xa.x, xa.y, xa.z, xa.w, xb.x, xb.y, xb.z, xb.w};
      const float ur[8] = {ua.x, ua.y, ua.z, ua.w, ub.x, ub.y, ub.z, ub.w};
#pragma unroll
      for (int i = 0; i < 8; ++i)
#pragma unroll
        for (int q = 0; q < 8; ++q) acc[i][q] = fmaf(xr[i], ur[q], acc[i][q]);
    }
  }

  const float4 bv0 = *(const float4*)(bias + i0 + tx * 8);
  const float4 bv1 = *(const float4*)(bias + i0 + tx * 8 + 4);
  const float bb[8] = {bv0.x, bv0.y, bv0.z, bv0.w, bv1.x, bv1.y, bv1.z, bv1.w};
#pragma unroll
  for (int i = 0; i < 8; ++i) {
    float4 o0, o1;
    o0.x = acc[i][0] + bb[0]; o0.y = acc[i][1] + bb[1];
    o0.z = acc[i][2] + bb[2]; o0.w = acc[i][3] + bb[3];
    o1.x = acc[i][4] + bb[4]; o1.y = acc[i][5] + bb[5];
    o1.z = acc[i][6] + bb[6]; o1.w = acc[i][7] + bb[7];
    float* dst = Ux + (size_t)(r0 + ty * 8 + i) * H_DIM + i0 + tx * 8;
    *(float4*)dst = o0;
    *(float4*)(dst + 4) = o1;
  }
}

// =====================================================================
// K2: scan. 64 blocks x 512 threads. bid = slice*8 + g.
//   group g = 32 batches; slice = 64 features.
//   No release/acquire cache-maintenance in the step loop:
//     - exchanged y goes through L3 via agent-scope RELAXED atomic 8B ops
//     - flags: relaxed store after __syncthreads (vmcnt drained = data at
//       coherence point); relaxed polling loads.
//   W/A fragments VGPR-resident (bfr[2][8] per wave). y_t staged to LDS
//   (bf16, XOR-swizzled) once per step; frags via ds_read_b128.
//   8 waves = (otype, ng, khalf); per wave M32 x N32 x K256 = 32 MFMA.
//   Own y state: 4 registers per thread (exact f32).
// =====================================================================
__device__ __forceinline__ unsigned swz(unsigned row, unsigned b) {
  return row * 1024u + (b ^ ((row & 7u) << 4));
}

__global__ __launch_bounds__(512, 1) void k2_scan(const float* __restrict__ W,
                                                  const float* __restrict__ Amat,
                                                  const float* __restrict__ y0,
                                                  const float* __restrict__ Ux,
                                                  const float* __restrict__ Wro,
                                                  __bf16* __restrict__ ybuf,      // 2*256*512 bf16
                                                  float* __restrict__ plog,       // [T][8][B]
                                                  unsigned int* __restrict__ flags) {  // 64 * 32
  __shared__ __align__(16) char Ylds[32 * 1024];   // 32 rows x 512 bf16, swizzled
  __shared__ float Xex[2][2][32][68];              // [otype][khalf][b][f] padded
  const int tid   = threadIdx.x;
  const int g     = blockIdx.x & 7;
  const int slice = blockIdx.x >> 3;
  const int fbase = slice * 64;

  const int l     = tid & 63;
  const int w     = tid >> 6;        // 0..7
  const int otype = w >> 2;          // 0 = pre (W), 1 = gate (A)
  const int ng    = (w >> 1) & 1;    // feature 32-group within 64
  const int khalf = w & 1;           // K 256-split

  const int bl     = tid >> 4;       // batch 0..31
  const int f0i    = (tid & 15) * 4; // feature 0..60
  const int b_glob = g * 32 + bl;

  // ---- own y0 state -> registers ----
  float4 yst = *(const float4*)(y0 + (size_t)b_glob * H_DIM + fbase + f0i);
  const float4 wrov = *(const float4*)(Wro + fbase + f0i);

  // ---- W/A fragments -> VGPRs (once) ----
  const int n0    = l & 15;
  const int kfrag = khalf * 256 + ((l >> 4) * 8);
  const float* Bsrc = otype ? Amat : W;
  bf16x8 bfr[2][8];
#pragma unroll
  for (int ks = 0; ks < 8; ++ks) {
#pragma unroll
    for (int h2 = 0; h2 < 2; ++h2) {
      const float* src = Bsrc + (size_t)(fbase + ng * 32 + n0 + h2 * 16) * H_DIM + kfrag + ks * 32;
      const float4 s0 = *(const float4*)src;
      const float4 s1 = *(const float4*)(src + 4);
      bf16x8 v;
      v[0] = (__bf16)s0.x; v[1] = (__bf16)s0.y; v[2] = (__bf16)s0.z; v[3] = (__bf16)s0.w;
      v[4] = (__bf16)s1.x; v[5] = (__bf16)s1.y; v[6] = (__bf16)s1.z; v[7] = (__bf16)s1.w;
      bfr[h2][ks] = v;
    }
  }

  const unsigned ra0  = (unsigned)(l & 15);
  const unsigned ra1  = ra0 + 16u;
  const unsigned coff = (unsigned)((l >> 4) * 16 + khalf * 512);

  for (int t = 0; t < T_DIM; ++t) {
    // input-path term: issue before spin (latency hides under the wait)
    const float4 uxv = *(const float4*)(Ux + ((size_t)t * B_DIM + b_glob) * H_DIM + fbase + f0i);

    // ---- wait for all 8 peer slices of this group (relaxed polls) ----
    if (t > 0) {
      const unsigned target = (unsigned)t;
      for (;;) {
        unsigned v = target;
        if (l < 8)
          v = __hip_atomic_load(flags + ((size_t)(l * 8 + g)) * 32,
                                __ATOMIC_RELAXED, __HIP_MEMORY_SCOPE_AGENT);
        if (__all(v >= target)) break;
        __builtin_amdgcn_s_sleep(1);
      }
      asm volatile("" ::: "memory");
    }

    // ---- stage y_t -> Ylds (bf16, swizzled) ----
    if (t == 0) {
#pragma unroll
      for (int j = 0; j < 8; ++j) {
        const int chunk = j * 512 + tid;          // 4096 x 8B chunks
        const unsigned row = (unsigned)chunk >> 7;
        const unsigned b8  = ((unsigned)chunk & 127u) * 8u;
        const float4 s = *(const float4*)(y0 + (size_t)(g * 32 + row) * H_DIM + (chunk & 127) * 4);
        bf16x4 v;
        v[0] = (__bf16)s.x; v[1] = (__bf16)s.y; v[2] = (__bf16)s.z; v[3] = (__bf16)s.w;
        *(bf16x4*)(Ylds + swz(row, b8)) = v;
      }
    } else {
      const ull* src = (const ull*)(ybuf + (size_t)(t & 1) * (B_DIM * H_DIM)
                                    + (size_t)g * 32 * H_DIM);
#pragma unroll
      for (int j = 0; j < 8; ++j) {
        const int chunk = j * 512 + tid;
        const unsigned row = (unsigned)chunk >> 7;
        const unsigned b8  = ((unsigned)chunk & 127u) * 8u;
        const ull v = __hip_atomic_load(src + chunk, __ATOMIC_RELAXED, __HIP_MEMORY_SCOPE_AGENT);
        *(ull*)(Ylds + swz(row, b8)) = v;
      }
    }
    __syncthreads();

    // ---- MFMA: 2M x 2N x 8K per wave ----
    f32x4 acc00 = {0.f, 0.f, 0.f, 0.f};
    f32x4 acc01 = {0.f, 0.f, 0.f, 0.f};
    f32x4 acc10 = {0.f, 0.f, 0.f, 0.f};
    f32x4 acc11 = {0.f, 0.f, 0.f, 0.f};
#pragma unroll
    for (int ks = 0; ks < 8; ++ks) {
      const unsigned kb = coff + (unsigned)ks * 64u;
      const bf16x8 a0 = *(const bf16x8*)(Ylds + swz(ra0, kb));
      const bf16x8 a1 = *(const bf16x8*)(Ylds + swz(ra1, kb));
      acc00 = __builtin_amdgcn_mfma_f32_16x16x32_bf16(a0, bfr[0][ks], acc00, 0, 0, 0);
      acc01 = __builtin_amdgcn_mfma_f32_16x16x32_bf16(a0, bfr[1][ks], acc01, 0, 0, 0);
      acc10 = __builtin_amdgcn_mfma_f32_16x16x32_bf16(a1, bfr[0][ks], acc10, 0, 0, 0);
      acc11 = __builtin_amdgcn_mfma_f32_16x16x32_bf16(a1, bfr[1][ks], acc11, 0, 0, 0);
    }

    // ---- partial-tile exchange ----
    {
      const int lr = (l >> 4) * 4;
      const int lc = l & 15;
#pragma unroll
      for (int r = 0; r < 4; ++r) {
        Xex[otype][khalf][lr + r][ng * 32 + lc]           = acc00[r];
        Xex[otype][khalf][lr + r][ng * 32 + lc + 16]      = acc01[r];
        Xex[otype][khalf][lr + r + 16][ng * 32 + lc]      = acc10[r];
        Xex[otype][khalf][lr + r + 16][ng * 32 + lc + 16] = acc11[r];
      }
    }
    __syncthreads();

    // ---- epilogue: combine K-halves, state update, publish ----
    {
      const float4 p0 = *(const float4*)&Xex[0][0][bl][f0i];
      const float4 p1 = *(const float4*)&Xex[0][1][bl][f0i];
      const float4 g0 = *(const float4*)&Xex[1][0][bl][f0i];
      const float4 g1 = *(const float4*)&Xex[1][1][bl][f0i];

      const float pr[4] = {p0.x + p1.x + uxv.x, p0.y + p1.y + uxv.y,
                           p0.z + p1.z + uxv.z, p0.w + p1.w + uxv.w};
      const float gv[4] = {g0.x + g1.x, g0.y + g1.y, g0.z + g1.z, g0.w + g1.w};
      const float yov[4] = {yst.x, yst.y, yst.z, yst.w};
      float yn[4];
#pragma unroll
      for (int j = 0; j < 4; ++j) {
        const float gate = 1.0f / (1.0f + expf(-gv[j]));
        yn[j] = yov[j] + 0.1f * tanhf(pr[j]) * gate;
      }
      yst.x = yn[0]; yst.y = yn[1]; yst.z = yn[2]; yst.w = yn[3];

      bf16x4 pk;
      pk[0] = (__bf16)yn[0]; pk[1] = (__bf16)yn[1];
      pk[2] = (__bf16)yn[2]; pk[3] = (__bf16)yn[3];
      ull pv;
      __builtin_memcpy(&pv, &pk, 8);
      ull* dst = (ull*)(ybuf + (size_t)((t + 1) & 1) * (B_DIM * H_DIM)
                        + (size_t)b_glob * H_DIM + fbase + f0i);
      __hip_atomic_store(dst, pv, __ATOMIC_RELAXED, __HIP_MEMORY_SCOPE_AGENT);

      float s = yn[0] * wrov.x + yn[1] * wrov.y + yn[2] * wrov.z + yn[3] * wrov.w;
      s += __shfl_xor(s, 1, 64);
      s += __shfl_xor(s, 2, 64);
      s += __shfl_xor(s, 4, 64);
      s += __shfl_xor(s, 8, 64);
      if ((tid & 15) == 0)
        plog[((size_t)t * 8 + slice) * B_DIM + b_glob] = s;
    }

    // ---- publish: barrier drains all waves' (write-through) stores ----
    __syncthreads();
    if (tid == 0)
      __hip_atomic_store(flags + (size_t)blockIdx.x * 32, (unsigned)(t + 1),
                         __ATOMIC_RELAXED, __HIP_MEMORY_SCOPE_AGENT);
  }
}

// =====================================================================
// K3: out[b][t] = bro + sum_{s<8} plog[t][s][b]
// =====================================================================
__global__ __launch_bounds__(256) void k3_out(const float* __restrict__ plog,
                                              const float* __restrict__ bro,
                                              float* __restrict__ out) {
  const int t = blockIdx.x;
  const int b = threadIdx.x;
  float s = bro[0];
#pragma unroll
  for (int col = 0; col < 8; ++col)
    s += plog[((size_t)t * 8 + col) * B_DIM + b];
  out[(size_t)b * T_DIM + t] = s;
}

// =====================================================================
extern "C" void kernel_launch(void* const* d_in, const int* in_sizes, int n_in,
                              void* d_out, int out_size, void* d_ws, size_t ws_size,
                              hipStream_t stream) {
  const float* x   = (const float*)d_in[0];
  const float* y0  = (const float*)d_in[1];
  const float* W   = (const float*)d_in[2];
  const float* U   = (const float*)d_in[3];
  const float* b   = (const float*)d_in[4];
  const float* A   = (const float*)d_in[5];
  const float* Wro = (const float*)d_in[6];
  const float* bro = (const float*)d_in[7];
  float* out = (float*)d_out;

  float* ws = (float*)d_ws;
  float* Ux = ws;                                               // 33,554,432 f32
  __bf16* ybuf = (__bf16*)(ws + (size_t)T_DIM * B_DIM * H_DIM); // 262,144 bf16
  float* plog = ws + (size_t)T_DIM * B_DIM * H_DIM + 131072;    // 524,288 f32
  unsigned int* flags = (unsigned int*)(plog + (size_t)T_DIM * 8 * B_DIM);  // 64*32 u32

  (void)in_sizes; (void)n_in; (void)out_size; (void)ws_size;

  hipMemsetAsync(flags, 0, 64 * 32 * sizeof(unsigned int), stream);

  dim3 g1(512, 4);
  k1_ux<<<g1, 256, 0, stream>>>(x, U, b, Ux);
  k2_scan<<<64, 512, 0, stream>>>(W, A, y0, Ux, Wro, ybuf, plog, flags);
  k3_out<<<256, 256, 0, stream>>>(plog, bro, out);
}